// Round 7
// baseline (245.359 us; speedup 1.0000x reference)
//
#include <hip/hip_runtime.h>

#define DDIM 256
#define HDIM 512

typedef float f32x4 __attribute__((ext_vector_type(4)));

// ---------------------------------------------------------------------------
// Fused precompute:
//   blocks [0, 512):  Wfused[i,:] = W_in[i,:] @ W1 (two 256-col halves/row)
//   blocks [512,514): bvec = b_in @ W1
//   blocks [514, ...): offsets[t] = lower_bound(batch, t), t in [0, G]
// ---------------------------------------------------------------------------
__global__ __launch_bounds__(256) void precompute_kernel(
    const float* __restrict__ W_in, const float* __restrict__ b_in,
    const float* __restrict__ W1, const int* __restrict__ batch,
    float* __restrict__ Wfused, float* __restrict__ bvec,
    int* __restrict__ offsets, int N, int G) {
  const int b = blockIdx.x;
  if (b < 2 * DDIM + 2) {
    __shared__ float vrow[DDIM];
    const bool is_b = (b >= 2 * DDIM);
    const int i = is_b ? 0 : (b >> 1);
    const int half = is_b ? (b - 2 * DDIM) : (b & 1);
    const float* src = is_b ? b_in : (W_in + (size_t)i * DDIM);
    vrow[threadIdx.x] = src[threadIdx.x];
    __syncthreads();

    const int j = half * 256 + threadIdx.x;
    float h = 0.f;
#pragma unroll 8
    for (int k = 0; k < DDIM; ++k) h += vrow[k] * W1[(size_t)k * HDIM + j];
    if (is_b) bvec[j] = h;
    else Wfused[(size_t)i * HDIM + j] = h;
  } else {
    const int t = (b - (2 * DDIM + 2)) * 256 + threadIdx.x;
    if (t > G) return;
    int lo = 0, hi = N;
    while (lo < hi) {
      const int mid = (lo + hi) >> 1;
      if (batch[mid] < t) lo = mid + 1;
      else hi = mid;
    }
    offsets[t] = lo;
  }
}

// ---------------------------------------------------------------------------
// Segment-sum, one block per segment. 4 waves; wave w owns rows ≡ w (mod 4),
// 4 independent float4 accumulator streams (16 rows in flight). Nontemporal
// loads: x is 1 GB pure streaming. LDS cross-wave reduce, direct store.
// ---------------------------------------------------------------------------
__global__ __launch_bounds__(256) void segsum_kernel(
    const float* __restrict__ x, const int* __restrict__ offsets,
    float* __restrict__ S, float* __restrict__ counts) {
  const int g = blockIdx.x;
  const int start = offsets[g], end = offsets[g + 1];
  __shared__ float red[3][DDIM];

  const int w  = threadIdx.x >> 6;          // wave 0..3
  const int c4 = (threadIdx.x & 63) << 2;   // column base
  const float* xp = x + c4;

  f32x4 a0 = {0.f, 0.f, 0.f, 0.f};
  f32x4 a1 = {0.f, 0.f, 0.f, 0.f};
  f32x4 a2 = {0.f, 0.f, 0.f, 0.f};
  f32x4 a3 = {0.f, 0.f, 0.f, 0.f};

  int i = start + w;
  for (; i + 12 < end; i += 16) {
    const f32x4 v0 = __builtin_nontemporal_load(
        reinterpret_cast<const f32x4*>(xp + (size_t)i * DDIM));
    const f32x4 v1 = __builtin_nontemporal_load(
        reinterpret_cast<const f32x4*>(xp + (size_t)(i + 4) * DDIM));
    const f32x4 v2 = __builtin_nontemporal_load(
        reinterpret_cast<const f32x4*>(xp + (size_t)(i + 8) * DDIM));
    const f32x4 v3 = __builtin_nontemporal_load(
        reinterpret_cast<const f32x4*>(xp + (size_t)(i + 12) * DDIM));
    a0 += v0;
    a1 += v1;
    a2 += v2;
    a3 += v3;
  }
  for (; i < end; i += 4) {
    const f32x4 v0 = __builtin_nontemporal_load(
        reinterpret_cast<const f32x4*>(xp + (size_t)i * DDIM));
    a0 += v0;
  }
  a0 += a1;
  a2 += a3;
  a0 += a2;

  if (w != 0) *reinterpret_cast<f32x4*>(&red[w - 1][c4]) = a0;
  __syncthreads();
  if (w == 0) {
#pragma unroll
    for (int r = 0; r < 3; ++r) {
      a0 += *reinterpret_cast<const f32x4*>(&red[r][c4]);
    }
    *reinterpret_cast<f32x4*>(S + (size_t)g * DDIM + c4) = a0;
    if (threadIdx.x == 0) counts[g] = (float)(end - start);
  }
}

// ---------------------------------------------------------------------------
// fp32 tiled GEMM, BM=BN=64, BK=64, 256 threads, 4x4 acc (2 B LDS / FMA).
// A-tile transposed in LDS; rows padded to 68 floats (16B-aligned, de-aliased
// banks). Next-tile global prefetch (8 float4 regs) before compute phase.
// Only 4 (K=256) / 8 (K=512) k-iterations -> half the barriers of BK=32.
// BIAS_MODE: 0 none; 1 +bias[j]; 2 +counts[row]*bvec[j]+bias[j]
// ---------------------------------------------------------------------------
template <bool RELU, int BIAS_MODE>
__global__ __launch_bounds__(256) void gemm64x64x64_kernel(
    int M, int N, int K, const float* __restrict__ A,
    const float* __restrict__ B, const float* __restrict__ bias,
    const float* __restrict__ bvec, const float* __restrict__ counts,
    float* __restrict__ C) {
  __shared__ float As[64][68];  // As[k][m], padded
  __shared__ float Bs[64][68];  // Bs[k][n], padded
  const int m0 = blockIdx.y * 64, n0 = blockIdx.x * 64;
  const int tid = threadIdx.x;
  const int tx = tid & 15, ty = tid >> 4;         // output 4x4 block coords
  const int ar = tid >> 2, ac = (tid & 3) << 4;   // A-load: row 0..63, col16
  const int br = tid >> 4, bc = (tid & 15) << 2;  // B-load: rows br+16q, col4

  const float* Ap = A + (size_t)(m0 + ar) * K + ac;
  const float* Bp = B + (size_t)br * N + n0 + bc;
  const size_t bstep = (size_t)16 * N;

  float acc[4][4] = {};
  float4 av[4], bv[4];
#pragma unroll
  for (int q = 0; q < 4; ++q) {
    av[q] = *reinterpret_cast<const float4*>(Ap + (q << 2));
    bv[q] = *reinterpret_cast<const float4*>(Bp + (size_t)q * bstep);
  }

  for (int k0 = 0; k0 < K; k0 += 64) {
    __syncthreads();
#pragma unroll
    for (int q = 0; q < 4; ++q) {
      As[ac + (q << 2) + 0][ar] = av[q].x;
      As[ac + (q << 2) + 1][ar] = av[q].y;
      As[ac + (q << 2) + 2][ar] = av[q].z;
      As[ac + (q << 2) + 3][ar] = av[q].w;
      *reinterpret_cast<float4*>(&Bs[br + (q << 4)][bc]) = bv[q];
    }
    __syncthreads();
    if (k0 + 64 < K) {  // prefetch next k-tile during compute
#pragma unroll
      for (int q = 0; q < 4; ++q) {
        av[q] = *reinterpret_cast<const float4*>(Ap + k0 + 64 + (q << 2));
        bv[q] = *reinterpret_cast<const float4*>(
            Bp + (size_t)(k0 + 64) * N + (size_t)q * bstep);
      }
    }
#pragma unroll 16
    for (int kk = 0; kk < 64; ++kk) {
      float a[4], b[4];
      *reinterpret_cast<float4*>(a) =
          *reinterpret_cast<const float4*>(&As[kk][ty << 2]);
      *reinterpret_cast<float4*>(b) =
          *reinterpret_cast<const float4*>(&Bs[kk][tx << 2]);
#pragma unroll
      for (int i2 = 0; i2 < 4; ++i2)
#pragma unroll
        for (int j2 = 0; j2 < 4; ++j2) acc[i2][j2] += a[i2] * b[j2];
    }
  }

  float4 bias4 = make_float4(0.f, 0.f, 0.f, 0.f);
  float4 bvec4 = make_float4(0.f, 0.f, 0.f, 0.f);
  if (BIAS_MODE >= 1)
    bias4 = *reinterpret_cast<const float4*>(bias + n0 + (tx << 2));
  if (BIAS_MODE == 2)
    bvec4 = *reinterpret_cast<const float4*>(bvec + n0 + (tx << 2));

#pragma unroll
  for (int i2 = 0; i2 < 4; ++i2) {
    const int row = m0 + (ty << 2) + i2;
    float cnt = 0.f;
    if (BIAS_MODE == 2) cnt = counts[row];
    float4 r;
    r.x = acc[i2][0] + bias4.x + cnt * bvec4.x;
    r.y = acc[i2][1] + bias4.y + cnt * bvec4.y;
    r.z = acc[i2][2] + bias4.z + cnt * bvec4.z;
    r.w = acc[i2][3] + bias4.w + cnt * bvec4.w;
    if (RELU) {
      r.x = fmaxf(r.x, 0.f);
      r.y = fmaxf(r.y, 0.f);
      r.z = fmaxf(r.z, 0.f);
      r.w = fmaxf(r.w, 0.f);
    }
    *reinterpret_cast<float4*>(C + (size_t)row * N + n0 + (tx << 2)) = r;
  }
}

extern "C" void kernel_launch(void* const* d_in, const int* in_sizes, int n_in,
                              void* d_out, int out_size, void* d_ws,
                              size_t ws_size, hipStream_t stream) {
  const float* x     = (const float*)d_in[0];
  const int*   batch = (const int*)d_in[1];
  const float* W_in  = (const float*)d_in[2];
  const float* b_in  = (const float*)d_in[3];
  const float* W1    = (const float*)d_in[4];
  const float* b1    = (const float*)d_in[5];
  const float* W2    = (const float*)d_in[6];
  const float* b2    = (const float*)d_in[7];
  float* out = (float*)d_out;

  const int N = in_sizes[1];       // 1,000,000 rows
  const int G = out_size / DDIM;   // 4096 segments

  // Workspace (floats): offsets[G+1] (int) | Wfused[256*512] | bvec[512]
  //                     | S[G*256] | counts[G] | H[G*512]
  int*   offsets = (int*)d_ws;
  float* Wfused  = (float*)d_ws + (G + 2);
  float* bvec    = Wfused + (size_t)DDIM * HDIM;
  float* S       = bvec + HDIM;
  float* counts  = S + (size_t)G * DDIM;
  float* H       = counts + G;

  // 1) Wfused = W_in @ W1, bvec = b_in @ W1, offsets = lower_bound(batch, ·)
  {
    const int nsearch = (G + 256) / 256;            // 17 blocks
    precompute_kernel<<<2 * DDIM + 2 + nsearch, 256, 0, stream>>>(
        W_in, b_in, W1, batch, Wfused, bvec, offsets, N, G);
  }

  // 2) S = segment_sum(x), counts[g] = |segment g|
  segsum_kernel<<<G, 256, 0, stream>>>(x, offsets, S, counts);

  // 3) H = relu(S @ Wfused + counts ⊗ bvec + b1)   [G, 512]
  {
    dim3 grid(HDIM / 64, G / 64);   // 8 x 64 = 512 blocks
    gemm64x64x64_kernel<true, 2><<<grid, 256, 0, stream>>>(
        G, HDIM, DDIM, S, Wfused, b1, bvec, counts, H);
  }
  // 4) out = H @ W2 + b2                           [G, 256]
  {
    dim3 grid(DDIM / 64, G / 64);   // 4 x 64 = 256 blocks
    gemm64x64x64_kernel<false, 1><<<grid, 256, 0, stream>>>(
        G, DDIM, HDIM, H, W2, b2, nullptr, nullptr, out);
  }
}

// Round 8
// 231.449 us; speedup vs baseline: 1.0601x; 1.0601x over previous
//
#include <hip/hip_runtime.h>

#define DDIM 256
#define HDIM 512

typedef float f32x4 __attribute__((ext_vector_type(4)));

// ---------------------------------------------------------------------------
// Fused precompute:
//   blocks [0, 512):  Wfused[i,:] = W_in[i,:] @ W1 (two 256-col halves/row)
//   blocks [512,514): bvec = b_in @ W1
//   blocks [514, ...): offsets[t] = lower_bound(batch, t), t in [0, G]
// ---------------------------------------------------------------------------
__global__ __launch_bounds__(256) void precompute_kernel(
    const float* __restrict__ W_in, const float* __restrict__ b_in,
    const float* __restrict__ W1, const int* __restrict__ batch,
    float* __restrict__ Wfused, float* __restrict__ bvec,
    int* __restrict__ offsets, int N, int G) {
  const int b = blockIdx.x;
  if (b < 2 * DDIM + 2) {
    __shared__ float vrow[DDIM];
    const bool is_b = (b >= 2 * DDIM);
    const int i = is_b ? 0 : (b >> 1);
    const int half = is_b ? (b - 2 * DDIM) : (b & 1);
    const float* src = is_b ? b_in : (W_in + (size_t)i * DDIM);
    vrow[threadIdx.x] = src[threadIdx.x];
    __syncthreads();

    const int j = half * 256 + threadIdx.x;
    float h = 0.f;
#pragma unroll 8
    for (int k = 0; k < DDIM; ++k) h += vrow[k] * W1[(size_t)k * HDIM + j];
    if (is_b) bvec[j] = h;
    else Wfused[(size_t)i * HDIM + j] = h;
  } else {
    const int t = (b - (2 * DDIM + 2)) * 256 + threadIdx.x;
    if (t > G) return;
    int lo = 0, hi = N;
    while (lo < hi) {
      const int mid = (lo + hi) >> 1;
      if (batch[mid] < t) lo = mid + 1;
      else hi = mid;
    }
    offsets[t] = lo;
  }
}

// ---------------------------------------------------------------------------
// Segment-sum, one block per segment. 4 waves; wave w owns rows ≡ w (mod 4),
// 4 independent float4 accumulator streams (16 rows in flight). Nontemporal
// loads: x is 1 GB pure streaming. LDS cross-wave reduce, direct store.
// ---------------------------------------------------------------------------
__global__ __launch_bounds__(256) void segsum_kernel(
    const float* __restrict__ x, const int* __restrict__ offsets,
    float* __restrict__ S, float* __restrict__ counts) {
  const int g = blockIdx.x;
  const int start = offsets[g], end = offsets[g + 1];
  __shared__ float red[3][DDIM];

  const int w  = threadIdx.x >> 6;          // wave 0..3
  const int c4 = (threadIdx.x & 63) << 2;   // column base
  const float* xp = x + c4;

  f32x4 a0 = {0.f, 0.f, 0.f, 0.f};
  f32x4 a1 = {0.f, 0.f, 0.f, 0.f};
  f32x4 a2 = {0.f, 0.f, 0.f, 0.f};
  f32x4 a3 = {0.f, 0.f, 0.f, 0.f};

  int i = start + w;
  for (; i + 12 < end; i += 16) {
    const f32x4 v0 = __builtin_nontemporal_load(
        reinterpret_cast<const f32x4*>(xp + (size_t)i * DDIM));
    const f32x4 v1 = __builtin_nontemporal_load(
        reinterpret_cast<const f32x4*>(xp + (size_t)(i + 4) * DDIM));
    const f32x4 v2 = __builtin_nontemporal_load(
        reinterpret_cast<const f32x4*>(xp + (size_t)(i + 8) * DDIM));
    const f32x4 v3 = __builtin_nontemporal_load(
        reinterpret_cast<const f32x4*>(xp + (size_t)(i + 12) * DDIM));
    a0 += v0;
    a1 += v1;
    a2 += v2;
    a3 += v3;
  }
  for (; i < end; i += 4) {
    const f32x4 v0 = __builtin_nontemporal_load(
        reinterpret_cast<const f32x4*>(xp + (size_t)i * DDIM));
    a0 += v0;
  }
  a0 += a1;
  a2 += a3;
  a0 += a2;

  if (w != 0) *reinterpret_cast<f32x4*>(&red[w - 1][c4]) = a0;
  __syncthreads();
  if (w == 0) {
#pragma unroll
    for (int r = 0; r < 3; ++r) {
      a0 += *reinterpret_cast<const f32x4*>(&red[r][c4]);
    }
    *reinterpret_cast<f32x4*>(S + (size_t)g * DDIM + c4) = a0;
    if (threadIdx.x == 0) counts[g] = (float)(end - start);
  }
}

// ---------------------------------------------------------------------------
// fp32 tiled GEMM, BM=BN=64, BK=32, 256 threads, 4x4 acc (2 B LDS / FMA).
// Double-buffered LDS: ONE barrier per k-iteration. A-tile transposed in
// LDS; rows padded to 68 floats (16B-aligned, bank de-aliased). Next-tile
// global loads issue before the compute phase (latency hidden under FMAs);
// LDS store of next tile goes to the idle buffer after compute.
// BIAS_MODE: 0 none; 1 +bias[j]; 2 +counts[row]*bvec[j]+bias[j]
// ---------------------------------------------------------------------------
template <bool RELU, int BIAS_MODE>
__global__ __launch_bounds__(256) void gemm64x64_kernel(
    int M, int N, int K, const float* __restrict__ A,
    const float* __restrict__ B, const float* __restrict__ bias,
    const float* __restrict__ bvec, const float* __restrict__ counts,
    float* __restrict__ C) {
  __shared__ float As[2][32][68];  // As[buf][k][m], padded
  __shared__ float Bs[2][32][68];  // Bs[buf][k][n], padded
  const int m0 = blockIdx.y * 64, n0 = blockIdx.x * 64;
  const int tid = threadIdx.x;
  const int tx = tid & 15, ty = tid >> 4;         // output 4x4 block coords
  const int ar = tid >> 2, ac = (tid & 3) << 3;   // A-load: row 0..63, col8
  const int br = tid >> 3, bc = (tid & 7) << 3;   // B-load: row 0..31, col8

  const float* Ap = A + (size_t)(m0 + ar) * K + ac;
  const float* Bp = B + (size_t)br * N + n0 + bc;

  float acc[4][4] = {};

  // Load tile 0 and stage into buffer 0.
  float4 av0 = *reinterpret_cast<const float4*>(Ap);
  float4 av1 = *reinterpret_cast<const float4*>(Ap + 4);
  float4 bv0 = *reinterpret_cast<const float4*>(Bp);
  float4 bv1 = *reinterpret_cast<const float4*>(Bp + 4);
  As[0][ac + 0][ar] = av0.x;
  As[0][ac + 1][ar] = av0.y;
  As[0][ac + 2][ar] = av0.z;
  As[0][ac + 3][ar] = av0.w;
  As[0][ac + 4][ar] = av1.x;
  As[0][ac + 5][ar] = av1.y;
  As[0][ac + 6][ar] = av1.z;
  As[0][ac + 7][ar] = av1.w;
  *reinterpret_cast<float4*>(&Bs[0][br][bc])     = bv0;
  *reinterpret_cast<float4*>(&Bs[0][br][bc + 4]) = bv1;
  __syncthreads();

  const int NT = K >> 5;
  int cur = 0;
  for (int t = 0; t < NT; ++t) {
    const bool more = (t + 1 < NT);
    if (more) {  // issue next-tile global loads; latency hides under compute
      const int kn = (t + 1) << 5;
      av0 = *reinterpret_cast<const float4*>(Ap + kn);
      av1 = *reinterpret_cast<const float4*>(Ap + kn + 4);
      bv0 = *reinterpret_cast<const float4*>(Bp + (size_t)kn * N);
      bv1 = *reinterpret_cast<const float4*>(Bp + (size_t)kn * N + 4);
    }
#pragma unroll
    for (int kk = 0; kk < 32; ++kk) {
      float a[4], b[4];
      *reinterpret_cast<float4*>(a) =
          *reinterpret_cast<const float4*>(&As[cur][kk][ty << 2]);
      *reinterpret_cast<float4*>(b) =
          *reinterpret_cast<const float4*>(&Bs[cur][kk][tx << 2]);
#pragma unroll
      for (int i2 = 0; i2 < 4; ++i2)
#pragma unroll
        for (int j2 = 0; j2 < 4; ++j2) acc[i2][j2] += a[i2] * b[j2];
    }
    if (more) {  // stage next tile into the idle buffer; one barrier/iter
      const int nxt = cur ^ 1;
      As[nxt][ac + 0][ar] = av0.x;
      As[nxt][ac + 1][ar] = av0.y;
      As[nxt][ac + 2][ar] = av0.z;
      As[nxt][ac + 3][ar] = av0.w;
      As[nxt][ac + 4][ar] = av1.x;
      As[nxt][ac + 5][ar] = av1.y;
      As[nxt][ac + 6][ar] = av1.z;
      As[nxt][ac + 7][ar] = av1.w;
      *reinterpret_cast<float4*>(&Bs[nxt][br][bc])     = bv0;
      *reinterpret_cast<float4*>(&Bs[nxt][br][bc + 4]) = bv1;
      __syncthreads();
      cur = nxt;
    }
  }

  float4 bias4 = make_float4(0.f, 0.f, 0.f, 0.f);
  float4 bvec4 = make_float4(0.f, 0.f, 0.f, 0.f);
  if (BIAS_MODE >= 1)
    bias4 = *reinterpret_cast<const float4*>(bias + n0 + (tx << 2));
  if (BIAS_MODE == 2)
    bvec4 = *reinterpret_cast<const float4*>(bvec + n0 + (tx << 2));

#pragma unroll
  for (int i2 = 0; i2 < 4; ++i2) {
    const int row = m0 + (ty << 2) + i2;
    float cnt = 0.f;
    if (BIAS_MODE == 2) cnt = counts[row];
    float4 r;
    r.x = acc[i2][0] + bias4.x + cnt * bvec4.x;
    r.y = acc[i2][1] + bias4.y + cnt * bvec4.y;
    r.z = acc[i2][2] + bias4.z + cnt * bvec4.z;
    r.w = acc[i2][3] + bias4.w + cnt * bvec4.w;
    if (RELU) {
      r.x = fmaxf(r.x, 0.f);
      r.y = fmaxf(r.y, 0.f);
      r.z = fmaxf(r.z, 0.f);
      r.w = fmaxf(r.w, 0.f);
    }
    *reinterpret_cast<float4*>(C + (size_t)row * N + n0 + (tx << 2)) = r;
  }
}

extern "C" void kernel_launch(void* const* d_in, const int* in_sizes, int n_in,
                              void* d_out, int out_size, void* d_ws,
                              size_t ws_size, hipStream_t stream) {
  const float* x     = (const float*)d_in[0];
  const int*   batch = (const int*)d_in[1];
  const float* W_in  = (const float*)d_in[2];
  const float* b_in  = (const float*)d_in[3];
  const float* W1    = (const float*)d_in[4];
  const float* b1    = (const float*)d_in[5];
  const float* W2    = (const float*)d_in[6];
  const float* b2    = (const float*)d_in[7];
  float* out = (float*)d_out;

  const int N = in_sizes[1];       // 1,000,000 rows
  const int G = out_size / DDIM;   // 4096 segments

  // Workspace (floats): offsets[G+1] (int) | Wfused[256*512] | bvec[512]
  //                     | S[G*256] | counts[G] | H[G*512]
  int*   offsets = (int*)d_ws;
  float* Wfused  = (float*)d_ws + (G + 2);
  float* bvec    = Wfused + (size_t)DDIM * HDIM;
  float* S       = bvec + HDIM;
  float* counts  = S + (size_t)G * DDIM;
  float* H       = counts + G;

  // 1) Wfused = W_in @ W1, bvec = b_in @ W1, offsets = lower_bound(batch, ·)
  {
    const int nsearch = (G + 256) / 256;            // 17 blocks
    precompute_kernel<<<2 * DDIM + 2 + nsearch, 256, 0, stream>>>(
        W_in, b_in, W1, batch, Wfused, bvec, offsets, N, G);
  }

  // 2) S = segment_sum(x), counts[g] = |segment g|
  segsum_kernel<<<G, 256, 0, stream>>>(x, offsets, S, counts);

  // 3) H = relu(S @ Wfused + counts ⊗ bvec + b1)   [G, 512]
  {
    dim3 grid(HDIM / 64, G / 64);   // 8 x 64 = 512 blocks
    gemm64x64_kernel<true, 2><<<grid, 256, 0, stream>>>(
        G, HDIM, DDIM, S, Wfused, b1, bvec, counts, H);
  }
  // 4) out = H @ W2 + b2                           [G, 256]
  {
    dim3 grid(DDIM / 64, G / 64);   // 4 x 64 = 256 blocks
    gemm64x64_kernel<false, 1><<<grid, 256, 0, stream>>>(
        G, DDIM, HDIM, H, W2, b2, nullptr, nullptr, out);
  }
}

// Round 9
// 194.424 us; speedup vs baseline: 1.2620x; 1.1904x over previous
//
#include <hip/hip_runtime.h>

#define DDIM 256
#define HDIM 512

typedef float f32x4 __attribute__((ext_vector_type(4)));
typedef short bf16x8 __attribute__((ext_vector_type(8)));

__device__ inline unsigned short f2bf(float f) {
  unsigned int u = __float_as_uint(f);
  u += 0x7fff + ((u >> 16) & 1);  // round-to-nearest-even
  return (unsigned short)(u >> 16);
}

// ---------------------------------------------------------------------------
// Fused precompute:
//   blocks [0,514):    WfT[j][i] = (W_in @ W1)[i][j] as bf16; bvec = b_in@W1
//   blocks [514,770):  W2T[n][k] = W2[k][n] as bf16   (transposed, k-contig)
//   blocks [770,...):  offsets[t] = lower_bound(batch, t)
// ---------------------------------------------------------------------------
__global__ __launch_bounds__(256) void precompute_kernel(
    const float* __restrict__ W_in, const float* __restrict__ b_in,
    const float* __restrict__ W1, const float* __restrict__ W2,
    const int* __restrict__ batch, unsigned short* __restrict__ WfT,
    unsigned short* __restrict__ W2T, float* __restrict__ bvec,
    int* __restrict__ offsets, int N, int G) {
  const int b = blockIdx.x;
  if (b < 2 * DDIM + 2) {
    __shared__ float vrow[DDIM];
    const bool is_b = (b >= 2 * DDIM);
    const int i = is_b ? 0 : (b >> 1);
    const int half = is_b ? (b - 2 * DDIM) : (b & 1);
    const float* src = is_b ? b_in : (W_in + (size_t)i * DDIM);
    vrow[threadIdx.x] = src[threadIdx.x];
    __syncthreads();

    const int j = half * 256 + threadIdx.x;
    float h = 0.f;
#pragma unroll 8
    for (int k = 0; k < DDIM; ++k) h += vrow[k] * W1[(size_t)k * HDIM + j];
    if (is_b) bvec[j] = h;
    else WfT[(size_t)j * DDIM + i] = f2bf(h);   // transposed bf16: [N=512][K=256]
  } else if (b < 2 * DDIM + 2 + DDIM) {
    const int n = b - (2 * DDIM + 2);           // W2T row: [N=256][K=512]
    for (int k = threadIdx.x; k < HDIM; k += 256)
      W2T[(size_t)n * HDIM + k] = f2bf(W2[(size_t)k * DDIM + n]);
  } else {
    const int t = (b - (2 * DDIM + 2 + DDIM)) * 256 + threadIdx.x;
    if (t > G) return;
    int lo = 0, hi = N;
    while (lo < hi) {
      const int mid = (lo + hi) >> 1;
      if (batch[mid] < t) lo = mid + 1;
      else hi = mid;
    }
    offsets[t] = lo;
  }
}

// ---------------------------------------------------------------------------
// Segment-sum, one block per segment; fp32 accumulate, bf16 store.
// 4 waves, 4 independent f32x4 streams (16 rows in flight), nontemporal x.
// ---------------------------------------------------------------------------
__global__ __launch_bounds__(256) void segsum_kernel(
    const float* __restrict__ x, const int* __restrict__ offsets,
    unsigned short* __restrict__ Sb, float* __restrict__ counts) {
  const int g = blockIdx.x;
  const int start = offsets[g], end = offsets[g + 1];
  __shared__ float red[3][DDIM];

  const int w  = threadIdx.x >> 6;          // wave 0..3
  const int c4 = (threadIdx.x & 63) << 2;   // column base
  const float* xp = x + c4;

  f32x4 a0 = {0.f, 0.f, 0.f, 0.f};
  f32x4 a1 = {0.f, 0.f, 0.f, 0.f};
  f32x4 a2 = {0.f, 0.f, 0.f, 0.f};
  f32x4 a3 = {0.f, 0.f, 0.f, 0.f};

  int i = start + w;
  for (; i + 12 < end; i += 16) {
    const f32x4 v0 = __builtin_nontemporal_load(
        reinterpret_cast<const f32x4*>(xp + (size_t)i * DDIM));
    const f32x4 v1 = __builtin_nontemporal_load(
        reinterpret_cast<const f32x4*>(xp + (size_t)(i + 4) * DDIM));
    const f32x4 v2 = __builtin_nontemporal_load(
        reinterpret_cast<const f32x4*>(xp + (size_t)(i + 8) * DDIM));
    const f32x4 v3 = __builtin_nontemporal_load(
        reinterpret_cast<const f32x4*>(xp + (size_t)(i + 12) * DDIM));
    a0 += v0;
    a1 += v1;
    a2 += v2;
    a3 += v3;
  }
  for (; i < end; i += 4) {
    const f32x4 v0 = __builtin_nontemporal_load(
        reinterpret_cast<const f32x4*>(xp + (size_t)i * DDIM));
    a0 += v0;
  }
  a0 += a1;
  a2 += a3;
  a0 += a2;

  if (w != 0) *reinterpret_cast<f32x4*>(&red[w - 1][c4]) = a0;
  __syncthreads();
  if (w == 0) {
#pragma unroll
    for (int r = 0; r < 3; ++r) {
      a0 += *reinterpret_cast<const f32x4*>(&red[r][c4]);
    }
    ushort4 sv;
    sv.x = f2bf(a0.x);
    sv.y = f2bf(a0.y);
    sv.z = f2bf(a0.z);
    sv.w = f2bf(a0.w);
    *reinterpret_cast<ushort4*>(Sb + (size_t)g * DDIM + c4) = sv;
    if (threadIdx.x == 0) counts[g] = (float)(end - start);
  }
}

// ---------------------------------------------------------------------------
// bf16 MFMA GEMM, no LDS: C[M,N] = A[M,K] @ BT[N,K]^T (+ epilogue).
// Block = 64x64 tile, 4 waves in 2x2; wave = 32x32 = 2x2 mfma_16x16x32 frags.
// Fragments loaded straight from L2/L3 as 16B/lane (operands are small and
// cache-resident). A: row=lane&15, k=(lane>>4)*8+e. BT row n gives B col n.
// D: col=lane&15, row=(lane>>4)*4+reg  (m89-verified).
// BIAS_MODE: 1 = +bias[col]; 2 = +counts[row]*bvec[col]+bias[col]
// ---------------------------------------------------------------------------
template <int K, bool RELU, int BIAS_MODE, bool OUTBF>
__global__ __launch_bounds__(256) void mfma_gemm_kernel(
    int N, const unsigned short* __restrict__ A,
    const unsigned short* __restrict__ BT, const float* __restrict__ bias,
    const float* __restrict__ bvec, const float* __restrict__ counts,
    float* __restrict__ Cf, unsigned short* __restrict__ Cb) {
  const int m0 = blockIdx.y * 64, n0 = blockIdx.x * 64;
  const int tid = threadIdx.x;
  const int wid = tid >> 6, lane = tid & 63;
  const int wr = wid >> 1, wc = wid & 1;
  const int l15 = lane & 15, lk8 = (lane >> 4) << 3;

  const unsigned short* Ap0 = A + (size_t)(m0 + wr * 32 + l15) * K + lk8;
  const unsigned short* Ap1 = Ap0 + (size_t)16 * K;
  const unsigned short* Bp0 = BT + (size_t)(n0 + wc * 32 + l15) * K + lk8;
  const unsigned short* Bp1 = Bp0 + (size_t)16 * K;

  f32x4 acc00 = {0.f, 0.f, 0.f, 0.f};
  f32x4 acc01 = {0.f, 0.f, 0.f, 0.f};
  f32x4 acc10 = {0.f, 0.f, 0.f, 0.f};
  f32x4 acc11 = {0.f, 0.f, 0.f, 0.f};

#pragma unroll
  for (int k0 = 0; k0 < K; k0 += 32) {
    const bf16x8 a0 = *reinterpret_cast<const bf16x8*>(Ap0 + k0);
    const bf16x8 a1 = *reinterpret_cast<const bf16x8*>(Ap1 + k0);
    const bf16x8 b0 = *reinterpret_cast<const bf16x8*>(Bp0 + k0);
    const bf16x8 b1 = *reinterpret_cast<const bf16x8*>(Bp1 + k0);
    acc00 = __builtin_amdgcn_mfma_f32_16x16x32_bf16(a0, b0, acc00, 0, 0, 0);
    acc01 = __builtin_amdgcn_mfma_f32_16x16x32_bf16(a0, b1, acc01, 0, 0, 0);
    acc10 = __builtin_amdgcn_mfma_f32_16x16x32_bf16(a1, b0, acc10, 0, 0, 0);
    acc11 = __builtin_amdgcn_mfma_f32_16x16x32_bf16(a1, b1, acc11, 0, 0, 0);
  }

  const int rbase = m0 + wr * 32 + ((lane >> 4) << 2);
  const int cbase = n0 + wc * 32 + l15;
#pragma unroll
  for (int si = 0; si < 2; ++si) {
#pragma unroll
    for (int sj = 0; sj < 2; ++sj) {
      const f32x4 ac = (si == 0) ? (sj == 0 ? acc00 : acc01)
                                 : (sj == 0 ? acc10 : acc11);
      const int col = cbase + sj * 16;
      const float bj = (BIAS_MODE >= 1) ? bias[col] : 0.f;
      const float vj = (BIAS_MODE == 2) ? bvec[col] : 0.f;
#pragma unroll
      for (int r = 0; r < 4; ++r) {
        const int row = rbase + si * 16 + r;
        float v = ac[r] + bj;
        if (BIAS_MODE == 2) v += counts[row] * vj;
        if (RELU) v = fmaxf(v, 0.f);
        if (OUTBF) Cb[(size_t)row * N + col] = f2bf(v);
        else       Cf[(size_t)row * N + col] = v;
      }
    }
  }
}

extern "C" void kernel_launch(void* const* d_in, const int* in_sizes, int n_in,
                              void* d_out, int out_size, void* d_ws,
                              size_t ws_size, hipStream_t stream) {
  const float* x     = (const float*)d_in[0];
  const int*   batch = (const int*)d_in[1];
  const float* W_in  = (const float*)d_in[2];
  const float* b_in  = (const float*)d_in[3];
  const float* W1    = (const float*)d_in[4];
  const float* b1    = (const float*)d_in[5];
  const float* W2    = (const float*)d_in[6];
  const float* b2    = (const float*)d_in[7];
  float* out = (float*)d_out;

  const int N = in_sizes[1];       // 1,000,000 rows
  const int G = out_size / DDIM;   // 4096 segments

  // Workspace layout (64B-aligned regions):
  char* wsb = (char*)d_ws;
  int* offsets = (int*)wsb;
  size_t off = (((size_t)(G + 1) * 4) + 63) & ~(size_t)63;
  unsigned short* WfT = (unsigned short*)(wsb + off);  off += (size_t)HDIM * DDIM * 2;
  unsigned short* W2T = (unsigned short*)(wsb + off);  off += (size_t)DDIM * HDIM * 2;
  float* bvec   = (float*)(wsb + off);                 off += (size_t)HDIM * 4;
  float* counts = (float*)(wsb + off);                 off += (size_t)G * 4;
  unsigned short* Sb = (unsigned short*)(wsb + off);   off += (size_t)G * DDIM * 2;
  unsigned short* Hb = (unsigned short*)(wsb + off);

  // 1) WfT = (W_in@W1)^T bf16, bvec = b_in@W1, W2T = W2^T bf16, offsets
  {
    const int nsearch = (G + 256) / 256;  // 17
    precompute_kernel<<<2 * DDIM + 2 + DDIM + nsearch, 256, 0, stream>>>(
        W_in, b_in, W1, W2, batch, WfT, W2T, bvec, offsets, N, G);
  }

  // 2) Sb = segment_sum(x) as bf16, counts[g] = |segment g|
  segsum_kernel<<<G, 256, 0, stream>>>(x, offsets, Sb, counts);

  // 3) Hb = relu(Sb @ Wf + counts ⊗ bvec + b1) as bf16   [G, 512]
  mfma_gemm_kernel<DDIM, true, 2, true>
      <<<dim3(HDIM / 64, G / 64), 256, 0, stream>>>(
          HDIM, Sb, WfT, b1, bvec, counts, nullptr, Hb);

  // 4) out = Hb @ W2 + b2 (fp32)                         [G, 256]
  mfma_gemm_kernel<HDIM, false, 1, false>
      <<<dim3(DDIM / 64, G / 64), 256, 0, stream>>>(
          DDIM, Hb, W2T, b2, nullptr, nullptr, out, nullptr);
}

// Round 10
// 190.029 us; speedup vs baseline: 1.2912x; 1.0231x over previous
//
#include <hip/hip_runtime.h>

#define DDIM 256
#define HDIM 512

typedef float f32x4 __attribute__((ext_vector_type(4)));
typedef short bf16x8 __attribute__((ext_vector_type(8)));

__device__ inline unsigned short f2bf(float f) {
  unsigned int u = __float_as_uint(f);
  u += 0x7fff + ((u >> 16) & 1);  // round-to-nearest-even
  return (unsigned short)(u >> 16);
}

// ---------------------------------------------------------------------------
// Fused main kernel. Weight-transform blocks FIRST so they overlap the
// HBM-bound segment stream instead of serializing before it:
//   blocks [0,514):      WfT[j][i] = (W_in@W1)[i][j] bf16; bvec = b_in@W1
//   blocks [514,770):    W2T[n][k] = W2[k][n] bf16
//   blocks [770,770+G):  segment g = b-770: binary-search row range,
//                        stream+sum rows of x, store Sb[g] bf16 + counts[g]
// ---------------------------------------------------------------------------
__global__ __launch_bounds__(256) void fused_main_kernel(
    const float* __restrict__ x, const int* __restrict__ batch,
    const float* __restrict__ W_in, const float* __restrict__ b_in,
    const float* __restrict__ W1, const float* __restrict__ W2,
    unsigned short* __restrict__ WfT, unsigned short* __restrict__ W2T,
    float* __restrict__ bvec, unsigned short* __restrict__ Sb,
    float* __restrict__ counts, int N, int G) {
  const int b = blockIdx.x;

  if (b < 2 * DDIM + 2) {  // Wfused^T (bf16) and bvec
    __shared__ float vrow[DDIM];
    const bool is_b = (b >= 2 * DDIM);
    const int i = is_b ? 0 : (b >> 1);
    const int half = is_b ? (b - 2 * DDIM) : (b & 1);
    const float* src = is_b ? b_in : (W_in + (size_t)i * DDIM);
    vrow[threadIdx.x] = src[threadIdx.x];
    __syncthreads();

    const int j = half * 256 + threadIdx.x;
    float h = 0.f;
#pragma unroll 8
    for (int k = 0; k < DDIM; ++k) h += vrow[k] * W1[(size_t)k * HDIM + j];
    if (is_b) bvec[j] = h;
    else WfT[(size_t)j * DDIM + i] = f2bf(h);  // [N=512][K=256]
    return;
  }
  if (b < 2 * DDIM + 2 + DDIM) {  // W2^T (bf16)
    const int n = b - (2 * DDIM + 2);  // [N=256][K=512]
    for (int k = threadIdx.x; k < HDIM; k += 256)
      W2T[(size_t)n * HDIM + k] = f2bf(W2[(size_t)k * DDIM + n]);
    return;
  }

  // ---- segment-sum block ----
  const int g = b - (2 * DDIM + 2 + DDIM);
  __shared__ int se[2];
  __shared__ float red[3][DDIM];

  if (threadIdx.x < 2) {  // lower_bound(batch, g) and (g+1)
    const int target = g + threadIdx.x;
    int lo = 0, hi = N;
    while (lo < hi) {
      const int mid = (lo + hi) >> 1;
      if (batch[mid] < target) lo = mid + 1;
      else hi = mid;
    }
    se[threadIdx.x] = lo;
  }
  __syncthreads();
  const int start = se[0], end = se[1];

  const int w  = threadIdx.x >> 6;          // wave 0..3
  const int c4 = (threadIdx.x & 63) << 2;   // column base
  const float* xp = x + c4;

  f32x4 a0 = {0.f, 0.f, 0.f, 0.f};
  f32x4 a1 = {0.f, 0.f, 0.f, 0.f};
  f32x4 a2 = {0.f, 0.f, 0.f, 0.f};
  f32x4 a3 = {0.f, 0.f, 0.f, 0.f};

  int i = start + w;
  for (; i + 12 < end; i += 16) {
    const f32x4 v0 = __builtin_nontemporal_load(
        reinterpret_cast<const f32x4*>(xp + (size_t)i * DDIM));
    const f32x4 v1 = __builtin_nontemporal_load(
        reinterpret_cast<const f32x4*>(xp + (size_t)(i + 4) * DDIM));
    const f32x4 v2 = __builtin_nontemporal_load(
        reinterpret_cast<const f32x4*>(xp + (size_t)(i + 8) * DDIM));
    const f32x4 v3 = __builtin_nontemporal_load(
        reinterpret_cast<const f32x4*>(xp + (size_t)(i + 12) * DDIM));
    a0 += v0;
    a1 += v1;
    a2 += v2;
    a3 += v3;
  }
  for (; i < end; i += 4) {
    const f32x4 v0 = __builtin_nontemporal_load(
        reinterpret_cast<const f32x4*>(xp + (size_t)i * DDIM));
    a0 += v0;
  }
  a0 += a1;
  a2 += a3;
  a0 += a2;

  if (w != 0) *reinterpret_cast<f32x4*>(&red[w - 1][c4]) = a0;
  __syncthreads();
  if (w == 0) {
#pragma unroll
    for (int r = 0; r < 3; ++r) {
      a0 += *reinterpret_cast<const f32x4*>(&red[r][c4]);
    }
    ushort4 sv;
    sv.x = f2bf(a0.x);
    sv.y = f2bf(a0.y);
    sv.z = f2bf(a0.z);
    sv.w = f2bf(a0.w);
    *reinterpret_cast<ushort4*>(Sb + (size_t)g * DDIM + c4) = sv;
    if (threadIdx.x == 0) counts[g] = (float)(end - start);
  }
}

// ---------------------------------------------------------------------------
// bf16 MFMA GEMM, no LDS: C[M,N] = A[M,K] @ BT[N,K]^T (+ epilogue).
// Block = 64x64 tile, 4 waves in 2x2; wave = 32x32 = 2x2 mfma_16x16x32 frags.
// Fragments loaded straight from L2/L3 as 16B/lane. A: row=lane&15,
// k=(lane>>4)*8+e. D: col=lane&15, row=(lane>>4)*4+reg  (m89-verified).
// BIAS_MODE: 1 = +bias[col]; 2 = +counts[row]*bvec[col]+bias[col]
// ---------------------------------------------------------------------------
template <int K, bool RELU, int BIAS_MODE, bool OUTBF>
__global__ __launch_bounds__(256) void mfma_gemm_kernel(
    int N, const unsigned short* __restrict__ A,
    const unsigned short* __restrict__ BT, const float* __restrict__ bias,
    const float* __restrict__ bvec, const float* __restrict__ counts,
    float* __restrict__ Cf, unsigned short* __restrict__ Cb) {
  const int m0 = blockIdx.y * 64, n0 = blockIdx.x * 64;
  const int tid = threadIdx.x;
  const int wid = tid >> 6, lane = tid & 63;
  const int wr = wid >> 1, wc = wid & 1;
  const int l15 = lane & 15, lk8 = (lane >> 4) << 3;

  const unsigned short* Ap0 = A + (size_t)(m0 + wr * 32 + l15) * K + lk8;
  const unsigned short* Ap1 = Ap0 + (size_t)16 * K;
  const unsigned short* Bp0 = BT + (size_t)(n0 + wc * 32 + l15) * K + lk8;
  const unsigned short* Bp1 = Bp0 + (size_t)16 * K;

  f32x4 acc00 = {0.f, 0.f, 0.f, 0.f};
  f32x4 acc01 = {0.f, 0.f, 0.f, 0.f};
  f32x4 acc10 = {0.f, 0.f, 0.f, 0.f};
  f32x4 acc11 = {0.f, 0.f, 0.f, 0.f};

#pragma unroll
  for (int k0 = 0; k0 < K; k0 += 32) {
    const bf16x8 a0 = *reinterpret_cast<const bf16x8*>(Ap0 + k0);
    const bf16x8 a1 = *reinterpret_cast<const bf16x8*>(Ap1 + k0);
    const bf16x8 b0 = *reinterpret_cast<const bf16x8*>(Bp0 + k0);
    const bf16x8 b1 = *reinterpret_cast<const bf16x8*>(Bp1 + k0);
    acc00 = __builtin_amdgcn_mfma_f32_16x16x32_bf16(a0, b0, acc00, 0, 0, 0);
    acc01 = __builtin_amdgcn_mfma_f32_16x16x32_bf16(a0, b1, acc01, 0, 0, 0);
    acc10 = __builtin_amdgcn_mfma_f32_16x16x32_bf16(a1, b0, acc10, 0, 0, 0);
    acc11 = __builtin_amdgcn_mfma_f32_16x16x32_bf16(a1, b1, acc11, 0, 0, 0);
  }

  const int rbase = m0 + wr * 32 + ((lane >> 4) << 2);
  const int cbase = n0 + wc * 32 + l15;
#pragma unroll
  for (int si = 0; si < 2; ++si) {
#pragma unroll
    for (int sj = 0; sj < 2; ++sj) {
      const f32x4 ac = (si == 0) ? (sj == 0 ? acc00 : acc01)
                                 : (sj == 0 ? acc10 : acc11);
      const int col = cbase + sj * 16;
      const float bj = (BIAS_MODE >= 1) ? bias[col] : 0.f;
      const float vj = (BIAS_MODE == 2) ? bvec[col] : 0.f;
#pragma unroll
      for (int r = 0; r < 4; ++r) {
        const int row = rbase + si * 16 + r;
        float v = ac[r] + bj;
        if (BIAS_MODE == 2) v += counts[row] * vj;
        if (RELU) v = fmaxf(v, 0.f);
        if (OUTBF) Cb[(size_t)row * N + col] = f2bf(v);
        else       Cf[(size_t)row * N + col] = v;
      }
    }
  }
}

extern "C" void kernel_launch(void* const* d_in, const int* in_sizes, int n_in,
                              void* d_out, int out_size, void* d_ws,
                              size_t ws_size, hipStream_t stream) {
  const float* x     = (const float*)d_in[0];
  const int*   batch = (const int*)d_in[1];
  const float* W_in  = (const float*)d_in[2];
  const float* b_in  = (const float*)d_in[3];
  const float* W1    = (const float*)d_in[4];
  const float* b1    = (const float*)d_in[5];
  const float* W2    = (const float*)d_in[6];
  const float* b2    = (const float*)d_in[7];
  float* out = (float*)d_out;

  const int N = in_sizes[1];       // 1,000,000 rows
  const int G = out_size / DDIM;   // 4096 segments

  // Workspace layout (64B-aligned regions):
  char* wsb = (char*)d_ws;
  size_t off = 0;
  unsigned short* WfT = (unsigned short*)(wsb + off);  off += (size_t)HDIM * DDIM * 2;
  unsigned short* W2T = (unsigned short*)(wsb + off);  off += (size_t)DDIM * HDIM * 2;
  float* bvec   = (float*)(wsb + off);                 off += (size_t)HDIM * 4;
  float* counts = (float*)(wsb + off);                 off += (size_t)G * 4;
  unsigned short* Sb = (unsigned short*)(wsb + off);   off += (size_t)G * DDIM * 2;
  unsigned short* Hb = (unsigned short*)(wsb + off);

  // 1) Weights transform (blocks first, overlaps segment stream) + segsum
  fused_main_kernel<<<2 * DDIM + 2 + DDIM + G, 256, 0, stream>>>(
      x, batch, W_in, b_in, W1, W2, WfT, W2T, bvec, Sb, counts, N, G);

  // 2) Hb = relu(Sb @ Wf + counts ⊗ bvec + b1) as bf16   [G, 512]
  mfma_gemm_kernel<DDIM, true, 2, true>
      <<<dim3(HDIM / 64, G / 64), 256, 0, stream>>>(
          HDIM, Sb, WfT, b1, bvec, counts, nullptr, Hb);

  // 3) out = Hb @ W2 + b2 (fp32)                         [G, 256]
  mfma_gemm_kernel<HDIM, false, 1, false>
      <<<dim3(DDIM / 64, G / 64), 256, 0, stream>>>(
          DDIM, Hb, W2T, b2, nullptr, nullptr, out, nullptr);
}

// Round 11
// 186.092 us; speedup vs baseline: 1.3185x; 1.0212x over previous
//
#include <hip/hip_runtime.h>

#define DDIM 256
#define HDIM 512

typedef float f32x4 __attribute__((ext_vector_type(4)));
typedef short bf16x8 __attribute__((ext_vector_type(8)));

__device__ inline unsigned short f2bf(float f) {
  unsigned int u = __float_as_uint(f);
  u += 0x7fff + ((u >> 16) & 1);  // round-to-nearest-even
  return (unsigned short)(u >> 16);
}

// ---------------------------------------------------------------------------
// Fused main kernel (unchanged from R9). Weight-transform blocks FIRST so
// they overlap the HBM-bound segment stream:
//   blocks [0,514):      WfT[j][i] = (W_in@W1)[i][j] bf16; bvec = b_in@W1
//   blocks [514,770):    W2T[n][k] = W2[k][n] bf16
//   blocks [770,770+G):  segment g: binary-search rows, stream+sum x,
//                        store Sb[g] bf16 + counts[g]
// ---------------------------------------------------------------------------
__global__ __launch_bounds__(256) void fused_main_kernel(
    const float* __restrict__ x, const int* __restrict__ batch,
    const float* __restrict__ W_in, const float* __restrict__ b_in,
    const float* __restrict__ W1, const float* __restrict__ W2,
    unsigned short* __restrict__ WfT, unsigned short* __restrict__ W2T,
    float* __restrict__ bvec, unsigned short* __restrict__ Sb,
    float* __restrict__ counts, int N, int G) {
  const int b = blockIdx.x;

  if (b < 2 * DDIM + 2) {  // Wfused^T (bf16) and bvec
    __shared__ float vrow[DDIM];
    const bool is_b = (b >= 2 * DDIM);
    const int i = is_b ? 0 : (b >> 1);
    const int half = is_b ? (b - 2 * DDIM) : (b & 1);
    const float* src = is_b ? b_in : (W_in + (size_t)i * DDIM);
    vrow[threadIdx.x] = src[threadIdx.x];
    __syncthreads();

    const int j = half * 256 + threadIdx.x;
    float h = 0.f;
#pragma unroll 8
    for (int k = 0; k < DDIM; ++k) h += vrow[k] * W1[(size_t)k * HDIM + j];
    if (is_b) bvec[j] = h;
    else WfT[(size_t)j * DDIM + i] = f2bf(h);  // [N=512][K=256]
    return;
  }
  if (b < 2 * DDIM + 2 + DDIM) {  // W2^T (bf16)
    const int n = b - (2 * DDIM + 2);  // [N=256][K=512]
    for (int k = threadIdx.x; k < HDIM; k += 256)
      W2T[(size_t)n * HDIM + k] = f2bf(W2[(size_t)k * DDIM + n]);
    return;
  }

  // ---- segment-sum block ----
  const int g = b - (2 * DDIM + 2 + DDIM);
  __shared__ int se[2];
  __shared__ float red[3][DDIM];

  if (threadIdx.x < 2) {  // lower_bound(batch, g) and (g+1)
    const int target = g + threadIdx.x;
    int lo = 0, hi = N;
    while (lo < hi) {
      const int mid = (lo + hi) >> 1;
      if (batch[mid] < target) lo = mid + 1;
      else hi = mid;
    }
    se[threadIdx.x] = lo;
  }
  __syncthreads();
  const int start = se[0], end = se[1];

  const int w  = threadIdx.x >> 6;          // wave 0..3
  const int c4 = (threadIdx.x & 63) << 2;   // column base
  const float* xp = x + c4;

  f32x4 a0 = {0.f, 0.f, 0.f, 0.f};
  f32x4 a1 = {0.f, 0.f, 0.f, 0.f};
  f32x4 a2 = {0.f, 0.f, 0.f, 0.f};
  f32x4 a3 = {0.f, 0.f, 0.f, 0.f};

  int i = start + w;
  for (; i + 12 < end; i += 16) {
    const f32x4 v0 = __builtin_nontemporal_load(
        reinterpret_cast<const f32x4*>(xp + (size_t)i * DDIM));
    const f32x4 v1 = __builtin_nontemporal_load(
        reinterpret_cast<const f32x4*>(xp + (size_t)(i + 4) * DDIM));
    const f32x4 v2 = __builtin_nontemporal_load(
        reinterpret_cast<const f32x4*>(xp + (size_t)(i + 8) * DDIM));
    const f32x4 v3 = __builtin_nontemporal_load(
        reinterpret_cast<const f32x4*>(xp + (size_t)(i + 12) * DDIM));
    a0 += v0;
    a1 += v1;
    a2 += v2;
    a3 += v3;
  }
  for (; i < end; i += 4) {
    const f32x4 v0 = __builtin_nontemporal_load(
        reinterpret_cast<const f32x4*>(xp + (size_t)i * DDIM));
    a0 += v0;
  }
  a0 += a1;
  a2 += a3;
  a0 += a2;

  if (w != 0) *reinterpret_cast<f32x4*>(&red[w - 1][c4]) = a0;
  __syncthreads();
  if (w == 0) {
#pragma unroll
    for (int r = 0; r < 3; ++r) {
      a0 += *reinterpret_cast<const f32x4*>(&red[r][c4]);
    }
    ushort4 sv;
    sv.x = f2bf(a0.x);
    sv.y = f2bf(a0.y);
    sv.z = f2bf(a0.z);
    sv.w = f2bf(a0.w);
    *reinterpret_cast<ushort4*>(Sb + (size_t)g * DDIM + c4) = sv;
    if (threadIdx.x == 0) counts[g] = (float)(end - start);
  }
}

// ---------------------------------------------------------------------------
// Fused MLP: one block per 16-row slab. Phase 1: H = relu(Sb@Wf + cnt*bvec
// + b1) -> LDS as bf16 (XOR-swizzled, both write and read sides). Phase 2:
// out = H @ W2 + b2 straight from LDS. Wave w owns H cols [128w,128w+128)
// in phase 1 and out cols [64w,64w+64) in phase 2. MFMA fragment idiom
// identical to the verified R8 kernel: A row=lane&15, B col=lane&15,
// k=(lane>>4)*8+e; D col=lane&15, row=(lane>>4)*4+reg.
// Swizzle: byte ^= (row&7)<<4 — rows 0-7 hit 8 distinct 16B slots, rows
// 8-15 repeat => 2-way (free, m136). 16B blocks stay contiguous (k0*16B
// aligned), so bf16x8 reads remain single ds_read_b128.
// ---------------------------------------------------------------------------
__global__ __launch_bounds__(256) void mlp_kernel(
    const unsigned short* __restrict__ Sb,
    const unsigned short* __restrict__ WfT,
    const unsigned short* __restrict__ W2T, const float* __restrict__ bvec,
    const float* __restrict__ b1, const float* __restrict__ b2,
    const float* __restrict__ counts, float* __restrict__ out) {
  __shared__ unsigned short Hs[16 * HDIM];  // 16 KB, swizzled layout
  const int tid = threadIdx.x;
  const int wid = tid >> 6, lane = tid & 63;
  const int l15 = lane & 15, lk8 = (lane >> 4) << 3;
  const int rbase = (lane >> 4) << 2;
  const int m0 = blockIdx.x * 16;

  // ---- Phase 1: H slab [16][512] ----
  const unsigned short* Ap = Sb + (size_t)(m0 + l15) * DDIM + lk8;
  const unsigned short* Bp = WfT + (size_t)(wid * 128 + l15) * DDIM + lk8;

  f32x4 acc[8] = {};
#pragma unroll
  for (int k0 = 0; k0 < DDIM; k0 += 32) {
    const bf16x8 a = *reinterpret_cast<const bf16x8*>(Ap + k0);
#pragma unroll
    for (int sj = 0; sj < 8; ++sj) {
      const bf16x8 bb =
          *reinterpret_cast<const bf16x8*>(Bp + (size_t)sj * 16 * DDIM + k0);
      acc[sj] = __builtin_amdgcn_mfma_f32_16x16x32_bf16(a, bb, acc[sj], 0, 0, 0);
    }
  }
  // epilogue -> LDS (swizzled bf16)
  char* hsb = (char*)Hs;
#pragma unroll
  for (int sj = 0; sj < 8; ++sj) {
    const int col = wid * 128 + sj * 16 + l15;
    const float vj = bvec[col];
    const float bj = b1[col];
#pragma unroll
    for (int r = 0; r < 4; ++r) {
      const int row = rbase + r;
      float v = acc[sj][r] + counts[m0 + row] * vj + bj;
      v = fmaxf(v, 0.f);
      const int byte = (row << 10) + (col << 1);
      *(unsigned short*)(hsb + (byte ^ ((row & 7) << 4))) = f2bf(v);
    }
  }
  __syncthreads();

  // ---- Phase 2: out slab [16][256] ----
  const unsigned short* B2p = W2T + (size_t)(wid * 64 + l15) * HDIM + lk8;
  f32x4 acc2[4] = {};
#pragma unroll
  for (int k0 = 0; k0 < HDIM; k0 += 32) {
    const int kb = (l15 << 10) + ((lk8 + k0) << 1);
    const bf16x8 a =
        *reinterpret_cast<const bf16x8*>(hsb + (kb ^ ((l15 & 7) << 4)));
#pragma unroll
    for (int sj = 0; sj < 4; ++sj) {
      const bf16x8 bb =
          *reinterpret_cast<const bf16x8*>(B2p + (size_t)sj * 16 * HDIM + k0);
      acc2[sj] = __builtin_amdgcn_mfma_f32_16x16x32_bf16(a, bb, acc2[sj], 0, 0, 0);
    }
  }
#pragma unroll
  for (int sj = 0; sj < 4; ++sj) {
    const int col = wid * 64 + sj * 16 + l15;
    const float bj = b2[col];
#pragma unroll
    for (int r = 0; r < 4; ++r) {
      const int row = m0 + rbase + r;
      out[(size_t)row * DDIM + col] = acc2[sj][r] + bj;
    }
  }
}

extern "C" void kernel_launch(void* const* d_in, const int* in_sizes, int n_in,
                              void* d_out, int out_size, void* d_ws,
                              size_t ws_size, hipStream_t stream) {
  const float* x     = (const float*)d_in[0];
  const int*   batch = (const int*)d_in[1];
  const float* W_in  = (const float*)d_in[2];
  const float* b_in  = (const float*)d_in[3];
  const float* W1    = (const float*)d_in[4];
  const float* b1    = (const float*)d_in[5];
  const float* W2    = (const float*)d_in[6];
  const float* b2    = (const float*)d_in[7];
  float* out = (float*)d_out;

  const int N = in_sizes[1];       // 1,000,000 rows
  const int G = out_size / DDIM;   // 4096 segments

  // Workspace layout (regions naturally aligned):
  char* wsb = (char*)d_ws;
  size_t off = 0;
  unsigned short* WfT = (unsigned short*)(wsb + off);  off += (size_t)HDIM * DDIM * 2;
  unsigned short* W2T = (unsigned short*)(wsb + off);  off += (size_t)DDIM * HDIM * 2;
  float* bvec   = (float*)(wsb + off);                 off += (size_t)HDIM * 4;
  float* counts = (float*)(wsb + off);                 off += (size_t)G * 4;
  unsigned short* Sb = (unsigned short*)(wsb + off);

  // 1) Weight transforms (first blocks, overlap the segment stream) + segsum
  fused_main_kernel<<<2 * DDIM + 2 + DDIM + G, 256, 0, stream>>>(
      x, batch, W_in, b_in, W1, W2, WfT, W2T, bvec, Sb, counts, N, G);

  // 2) out = relu(Sb @ Wf + counts ⊗ bvec + b1) @ W2 + b2, one dispatch
  mlp_kernel<<<G / 16, 256, 0, stream>>>(Sb, WfT, W2T, bvec, b1, b2, counts,
                                         out);
}